// Round 3
// baseline (3998.480 us; speedup 1.0000x reference)
//
#include <hip/hip_runtime.h>
#include <math.h>

// Problem constants
#define B_ 8
#define C_ 64
#define L_ 100
#define N_ 100
#define SIDE_ 144
#define DEMB_ 128
#define OUTC_ 6400   // C*L
#define TOPK_ 20
#define G_ 64

// Workspace layout (floats). Peak ~35.93M floats ~= 143.7 MB.
// Reuse: HS<-SAIN region, TIN<-H region, TOUT<-HP region (lifetimes disjoint).
#define OFF_SAIN 0
#define OFF_H    5120000
#define OFF_HP   10240000
#define OFF_GX   15360000
#define OFF_HS   0
#define OFF_TIN  5120000
#define OFF_TOUT 10240000
#define OFF_DEMB 35840000
#define OFF_F1   35840512
#define OFF_F2   35841312
#define OFF_ATT  35842112

__device__ __forceinline__ float sigf(float x) { return 1.f / (1.f + expf(-x)); }

// ---------------------------------------------------------------- K0: diffusion emb
__global__ __launch_bounds__(512) void k0_demb(const float* __restrict__ de,
                                               const float* __restrict__ dpw,
                                               const float* __restrict__ dpb,
                                               float* __restrict__ demb) {
  int tid = threadIdx.x;          // 512 = 8 b * 64 c
  int b = tid >> 6, c = tid & 63;
  float a = dpb[c];
  for (int k = 0; k < DEMB_; ++k) a += de[b * DEMB_ + k] * dpw[c * DEMB_ + k];
  demb[b * 64 + c] = a;
}

// ---------------------------------------------------------------- K1: x + demb + cond proj -> sa_in [b][n][l*64+c]
__global__ __launch_bounds__(256) void k1_sain(const float* __restrict__ x,
                                               const float* __restrict__ ci_g,
                                               const float* __restrict__ cw_g,
                                               const float* __restrict__ cb,
                                               const float* __restrict__ demb,
                                               float* __restrict__ sain) {
  int l = blockIdx.x, b = blockIdx.y, tid = threadIdx.x;
  __shared__ float ci[72][100];   // chunk of cond_info [s][n]
  __shared__ float cw[72][64];    // chunk of cond_w transposed [s][c]
  __shared__ float xt[64][101];   // x tile [c][n], pitch 101 -> conflict-free reads
  float acc[25];
#pragma unroll
  for (int i = 0; i < 25; ++i) acc[i] = 0.f;
  for (int idx = tid; idx < 6400; idx += 256) {
    int c = idx / 100, n = idx - c * 100;
    xt[c][n] = x[((b * C_ + c) * L_ + l) * N_ + n];
  }
  for (int ch = 0; ch < 2; ++ch) {
    int s0 = ch * 72;
    __syncthreads();
    for (int idx = tid; idx < 7200; idx += 256) {
      int s = idx / 100, n = idx - s * 100;
      ci[s][n] = ci_g[((b * SIDE_ + s0 + s) * L_ + l) * N_ + n];
    }
    for (int idx = tid; idx < 4608; idx += 256) {
      int s = idx >> 6, c = idx & 63;
      cw[s][c] = cw_g[c * SIDE_ + s0 + s];
    }
    __syncthreads();
#pragma unroll
    for (int i = 0; i < 25; ++i) {
      int o = i * 256 + tid;
      int n = o >> 6, c = o & 63;
      float a = 0.f;
      for (int s = 0; s < 72; ++s) a += cw[s][c] * ci[s][n];
      acc[i] += a;
    }
  }
#pragma unroll
  for (int i = 0; i < 25; ++i) {
    int o = i * 256 + tid;
    int n = o >> 6, c = o & 63;
    sain[(b * N_ + n) * OUTC_ + l * 64 + c] =
        acc[i] + xt[c][n] + demb[b * 64 + c] + cb[c];
  }
}

// ---------------------------------------------------------------- K3: h = sa_in @ sa_W  (M=800,K=6400,N=6400 fp32)
// 64x128 tile, BK=16, 256 threads, 4x8 acc/thread.
// Inner-loop arithmetic: per k, 3x ds_read_b128 (~36 cyc) vs 32 FMA (~64 cyc) -> VALU-bound.
__global__ __launch_bounds__(256) void k3_gemm(const float* __restrict__ A,
                                               const float* __restrict__ Bm,
                                               float* __restrict__ Cm) {
  __shared__ float As[16][64];    // k-major A tile
  __shared__ float Bs[16][128];
  int bx = blockIdx.x, by = blockIdx.y, tid = threadIdx.x;
  int tx = tid & 15, ty = tid >> 4;
  int row0 = by * 64, col0 = bx * 128;
  float acc[4][8];
#pragma unroll
  for (int i = 0; i < 4; ++i)
#pragma unroll
    for (int j = 0; j < 8; ++j) acc[i][j] = 0.f;
  int am = tid >> 2, ak = (tid & 3) * 4;    // A: 64 rows x 16 k, 1 float4/thread
  int bk = tid >> 4, bj = (tid & 15) * 8;   // B: 16 k x 128 cols, 2 float4/thread
  int arow = row0 + am;
  bool avalid = arow < 800;
  const float* aptr = A + arow * 6400 + ak;
  for (int k0 = 0; k0 < 6400; k0 += 16) {
    float4 av = make_float4(0.f, 0.f, 0.f, 0.f);
    if (avalid) av = *(const float4*)(aptr + k0);
    const float* bp = &Bm[(size_t)(k0 + bk) * 6400 + col0 + bj];
    float4 bv0 = *(const float4*)bp;
    float4 bv1 = *(const float4*)(bp + 4);
    __syncthreads();
    As[ak + 0][am] = av.x; As[ak + 1][am] = av.y;
    As[ak + 2][am] = av.z; As[ak + 3][am] = av.w;
    *(float4*)&Bs[bk][bj] = bv0;
    *(float4*)&Bs[bk][bj + 4] = bv1;
    __syncthreads();
#pragma unroll
    for (int k = 0; k < 16; ++k) {
      float4 a4 = *(const float4*)&As[k][ty * 4];
      float4 b0 = *(const float4*)&Bs[k][tx * 8];
      float4 b1 = *(const float4*)&Bs[k][tx * 8 + 4];
      float ar[4] = {a4.x, a4.y, a4.z, a4.w};
      float br[8] = {b0.x, b0.y, b0.z, b0.w, b1.x, b1.y, b1.z, b1.w};
#pragma unroll
      for (int i = 0; i < 4; ++i)
#pragma unroll
        for (int j = 0; j < 8; ++j) acc[i][j] += ar[i] * br[j];
    }
  }
#pragma unroll
  for (int i = 0; i < 4; ++i) {
    int r = row0 + ty * 4 + i;
    if (r < 800) {
      float4 v0 = make_float4(acc[i][0], acc[i][1], acc[i][2], acc[i][3]);
      float4 v1 = make_float4(acc[i][4], acc[i][5], acc[i][6], acc[i][7]);
      *(float4*)&Cm[r * 6400 + col0 + tx * 8] = v0;
      *(float4*)&Cm[r * 6400 + col0 + tx * 8 + 4] = v1;
    }
  }
}

// ---------------------------------------------------------------- K4: f1/f2 = h @ a1, h @ a2
__global__ __launch_bounds__(256) void k4_f12(const float* __restrict__ h,
                                              const float* __restrict__ sa_a,
                                              float* __restrict__ f1,
                                              float* __restrict__ f2) {
  int row = blockIdx.x, tid = threadIdx.x;
  __shared__ float r1[256], r2[256];
  float a1 = 0.f, a2 = 0.f;
  for (int i = tid; i < 6400; i += 256) {
    float hv = h[row * 6400 + i];
    a1 += hv * sa_a[i];
    a2 += hv * sa_a[6400 + i];
  }
  r1[tid] = a1; r2[tid] = a2;
  __syncthreads();
  for (int s = 128; s > 0; s >>= 1) {
    if (tid < s) { r1[tid] += r1[tid + s]; r2[tid] += r2[tid + s]; }
    __syncthreads();
  }
  if (tid == 0) { f1[row] = r1[0]; f2[row] = r2[0]; }
}

// ---------------------------------------------------------------- K5: e -> top20/col mask -> row softmax -> att
// adj = softmax(relu(GL GL^T)) + I is strictly > 0, so the where() is a no-op.
__global__ __launch_bounds__(128) void k5_att(const float* __restrict__ f1,
                                              const float* __restrict__ f2,
                                              float* __restrict__ att) {
  int b = blockIdx.x, tid = threadIdx.x;  // 128 threads
  __shared__ float E[100][101];
  __shared__ float M2[100][101];
  __shared__ float f1s[100], f2s[100];
  if (tid < 100) { f1s[tid] = f1[b * 100 + tid]; f2s[tid] = f2[b * 100 + tid]; }
  __syncthreads();
  for (int idx = tid; idx < 10000; idx += 128) {
    int i = idx / 100, j = idx - i * 100;
    float v = f1s[i] + f2s[j];
    E[i][j] = v > 0.f ? v : 0.01f * v;   // leaky_relu 0.01
  }
  __syncthreads();
  if (tid < 100) {        // per-column top-20 over rows i (ties -> lowest index, matches lax.top_k)
    int j = tid;
    unsigned long long c0 = 0ull, c1 = 0ull;
    for (int it = 0; it < TOPK_; ++it) {
      float best = -1e30f; int bi = 0;
      for (int i = 0; i < 100; ++i) {
        bool used = (i < 64) ? ((c0 >> i) & 1ull) : ((c1 >> (i - 64)) & 1ull);
        float v = E[i][j];
        if (!used && v > best) { best = v; bi = i; }
      }
      if (bi < 64) c0 |= 1ull << bi; else c1 |= 1ull << (bi - 64);
    }
    for (int i = 0; i < 100; ++i) {
      bool sel = (i < 64) ? ((c0 >> i) & 1ull) : ((c1 >> (i - 64)) & 1ull);
      M2[i][j] = sel ? E[i][j] : 0.f;    // multiplicative mask, per source
    }
  }
  __syncthreads();
  if (tid < 100) {        // row softmax over j
    int i = tid;
    float mx = -1e30f;
    for (int j = 0; j < 100; ++j) mx = fmaxf(mx, M2[i][j]);
    float sm = 0.f;
    for (int j = 0; j < 100; ++j) { float e = expf(M2[i][j] - mx); M2[i][j] = e; sm += e; }
    float inv = 1.f / sm;
    for (int j = 0; j < 100; ++j) att[(b * 100 + i) * 100 + j] = M2[i][j] * inv;
  }
}

// ---------------------------------------------------------------- K5b: hp = relu(att @ h)  [b][node][f]
__global__ __launch_bounds__(256) void k5b_hprime(const float* __restrict__ h,
                                                  const float* __restrict__ att,
                                                  float* __restrict__ hp) {
  int ft = blockIdx.x, b = blockIdx.y, tid = threadIdx.x;
  __shared__ float A[100][101];
  for (int idx = tid; idx < 10000; idx += 256)
    A[idx / 100][idx % 100] = att[b * 10000 + idx];
  __syncthreads();
  int cidx = tid & 63, g = tid >> 6;
  int col = ft * 64 + cidx;
  float acc[25];
#pragma unroll
  for (int r = 0; r < 25; ++r) acc[r] = 0.f;
  for (int k = 0; k < 100; ++k) {
    float hv = h[(b * 100 + k) * 6400 + col];
#pragma unroll
    for (int r = 0; r < 25; ++r) acc[r] += A[g * 25 + r][k] * hv;
  }
#pragma unroll
  for (int r = 0; r < 25; ++r) {
    float v = acc[r];
    hp[(b * 100 + (g * 25 + r)) * 6400 + col] = v > 0.f ? v : 0.f;
  }
}

// ---------------------------------------------------------------- K6: LSTM input precompute gx[t][l][j]
// seq[t][l][c] = hp[b=t/100][node=l][f=c*100 + t%100]
__global__ __launch_bounds__(256) void k6_gx(const float* __restrict__ hp,
                                             const float* __restrict__ Wih,
                                             const float* __restrict__ bih,
                                             const float* __restrict__ bhh,
                                             float* __restrict__ gx) {
  int t = blockIdx.x, tid = threadIdx.x;
  int b = t / 100, n2 = t - b * 100;
  __shared__ float inb[100][64];
  for (int idx = tid; idx < 6400; idx += 256) {
    int l = idx >> 6, c = idx & 63;
    inb[l][c] = hp[(b * 100 + l) * 6400 + c * 100 + n2];
  }
  float wr[64];
#pragma unroll
  for (int c = 0; c < 64; ++c) wr[c] = Wih[tid * 64 + c];
  float base = bih[tid] + bhh[tid];
  __syncthreads();
  for (int l = 0; l < 100; ++l) {
    float a = base;
#pragma unroll
    for (int c = 0; c < 64; ++c) a += wr[c] * inb[l][c];
    gx[(t * 100 + l) * 256 + tid] = a;
  }
}

// ---------------------------------------------------------------- K7: LSTM recurrence, 1 block per batch-lane l
__global__ __launch_bounds__(256) void k7_lstm(const float* __restrict__ gx,
                                               const float* __restrict__ Whh,
                                               float* __restrict__ hs) {
  int l = blockIdx.x, j = threadIdx.x;
  __shared__ float hsh[64];
  __shared__ float gl[256];
  float wr[64];
#pragma unroll
  for (int k = 0; k < 64; ++k) wr[k] = Whh[j * 64 + k];
  if (j < 64) hsh[j] = 0.f;
  float c = 0.f;
  __syncthreads();
  float gcur = gx[l * 256 + j];
  for (int t = 0; t < 800; ++t) {
    float gnext = (t < 799) ? gx[((t + 1) * 100 + l) * 256 + j] : 0.f;  // prefetch
    float a = gcur;
#pragma unroll
    for (int k = 0; k < 64; ++k) a += wr[k] * hsh[k];
    gl[j] = a;
    __syncthreads();
    if (j < 64) {
      float ig = sigf(gl[j]);
      float fg = sigf(gl[64 + j]);
      float gg = tanhf(gl[128 + j]);
      float og = sigf(gl[192 + j]);
      c = fg * c + ig * gg;
      float hn = og * tanhf(c);
      hsh[j] = hn;
      hs[(t * 100 + l) * 64 + j] = hn;
    }
    __syncthreads();
    gcur = gnext;
  }
}

// ---------------------------------------------------------------- K8: y2 = silu(hs @ lin_w.T + b) -> tin[s][b][l][c]
__global__ __launch_bounds__(256) void k8_y2(const float* __restrict__ hs,
                                             const float* __restrict__ lin_w,
                                             const float* __restrict__ lin_b,
                                             float* __restrict__ tin) {
  int t = blockIdx.x, tid = threadIdx.x;
  int b = t / 100, n2 = t - b * 100;
  __shared__ float hsl[100][64];
  for (int idx = tid; idx < 6400; idx += 256)
    hsl[idx >> 6][idx & 63] = hs[t * 6400 + idx];
  int c = tid & 63;
  float lw[64];
#pragma unroll
  for (int k = 0; k < 64; ++k) lw[k] = lin_w[c * 64 + k];
  float bias = lin_b[c];
  __syncthreads();
#pragma unroll
  for (int i = 0; i < 25; ++i) {
    int o = i * 256 + tid;
    int l = o >> 6;
    float a = bias;
#pragma unroll
    for (int k = 0; k < 64; ++k) a += lw[k] * hsl[l][k];
    tin[((n2 * 8 + b) * 100 + l) * 64 + c] = a * sigf(a);   // silu
  }
}

// ---------------------------------------------------------------- K9: transformer encoder layer, 1 block per bb
__global__ __launch_bounds__(256) void k9_tr(const float* __restrict__ tin,
                                             float* __restrict__ tout,
                                             const float* __restrict__ in_w, const float* __restrict__ in_b,
                                             const float* __restrict__ ow, const float* __restrict__ ob,
                                             const float* __restrict__ f1w, const float* __restrict__ f1b,
                                             const float* __restrict__ f2w, const float* __restrict__ f2b,
                                             const float* __restrict__ g1, const float* __restrict__ b1,
                                             const float* __restrict__ g2, const float* __restrict__ b2) {
  int bb = blockIdx.x;
  int b = bb / 100, l = bb - b * 100;
  int tid = threadIdx.x;
  __shared__ float X[100][65];
  __shared__ float C2[100][65];
  __shared__ float TMP[100][65];
  __shared__ float Sc[100][101];
  __shared__ float Qh[100][9], Kh[100][9], Vh[100][9];
  __shared__ float red1[100], red2[100];
  for (int idx = tid; idx < 6400; idx += 256) {
    int s = idx >> 6, c = idx & 63;
    X[s][c] = tin[((s * 8 + b) * 100 + l) * 64 + c];
    C2[s][c] = 0.f;
  }
  __syncthreads();
  for (int h = 0; h < 8; ++h) {
    for (int idx = tid; idx < 800; idx += 256) {   // per-head qkv
      int s = idx >> 3, e = idx & 7, r = h * 8 + e;
      float aq = in_b[r], ak = in_b[64 + r], av = in_b[128 + r];
      for (int c = 0; c < 64; ++c) {
        float xv = X[s][c];
        aq += xv * in_w[r * 64 + c];
        ak += xv * in_w[(64 + r) * 64 + c];
        av += xv * in_w[(128 + r) * 64 + c];
      }
      Qh[s][e] = aq; Kh[s][e] = ak; Vh[s][e] = av;
    }
    __syncthreads();
    for (int idx = tid; idx < 10000; idx += 256) { // scores
      int si = idx / 100, tj = idx - si * 100;
      float a = 0.f;
#pragma unroll
      for (int e = 0; e < 8; ++e) a += Qh[si][e] * Kh[tj][e];
      Sc[si][tj] = a * 0.35355339059327373f;
    }
    __syncthreads();
    if (tid < 100) {                               // softmax over t
      float mx = -1e30f;
      for (int j = 0; j < 100; ++j) mx = fmaxf(mx, Sc[tid][j]);
      float sm = 0.f;
      for (int j = 0; j < 100; ++j) { float e = expf(Sc[tid][j] - mx); Sc[tid][j] = e; sm += e; }
      float inv = 1.f / sm;
      for (int j = 0; j < 100; ++j) Sc[tid][j] *= inv;
    }
    __syncthreads();
    for (int idx = tid; idx < 800; idx += 256) {   // ctx
      int s = idx >> 3, e = idx & 7;
      float a = 0.f;
      for (int j = 0; j < 100; ++j) a += Sc[s][j] * Vh[j][e];
      C2[s][h * 8 + e] = a;
    }
    __syncthreads();
  }
  // attn out proj + residual
  for (int idx = tid; idx < 6400; idx += 256) {
    int s = idx >> 6, c = idx & 63;
    float a = ob[c];
    for (int d = 0; d < 64; ++d) a += C2[s][d] * ow[c * 64 + d];
    TMP[s][c] = X[s][c] + a;
  }
  __syncthreads();
  if (tid < 100) {   // LN1 stats (biased var, eps 1e-5)
    float mu = 0.f;
    for (int c = 0; c < 64; ++c) mu += TMP[tid][c];
    mu *= (1.f / 64.f);
    float var = 0.f;
    for (int c = 0; c < 64; ++c) { float d = TMP[tid][c] - mu; var += d * d; }
    red1[tid] = mu; red2[tid] = rsqrtf(var * (1.f / 64.f) + 1e-5f);
  }
  __syncthreads();
  for (int idx = tid; idx < 6400; idx += 256) {
    int s = idx >> 6, c = idx & 63;
    X[s][c] = (TMP[s][c] - red1[s]) * red2[s] * g1[c] + b1[c];
  }
  __syncthreads();
  for (int idx = tid; idx < 6400; idx += 256) {   // ff1 + exact gelu
    int s = idx >> 6, f = idx & 63;
    float a = f1b[f];
    for (int c = 0; c < 64; ++c) a += X[s][c] * f1w[f * 64 + c];
    C2[s][f] = 0.5f * a * (1.f + erff(a * 0.7071067811865475f));
  }
  __syncthreads();
  for (int idx = tid; idx < 6400; idx += 256) {   // ff2 + residual
    int s = idx >> 6, c = idx & 63;
    float a = f2b[c];
    for (int f = 0; f < 64; ++f) a += C2[s][f] * f2w[c * 64 + f];
    TMP[s][c] = X[s][c] + a;
  }
  __syncthreads();
  if (tid < 100) {   // LN2 stats
    float mu = 0.f;
    for (int c = 0; c < 64; ++c) mu += TMP[tid][c];
    mu *= (1.f / 64.f);
    float var = 0.f;
    for (int c = 0; c < 64; ++c) { float d = TMP[tid][c] - mu; var += d * d; }
    red1[tid] = mu; red2[tid] = rsqrtf(var * (1.f / 64.f) + 1e-5f);
  }
  __syncthreads();
  for (int idx = tid; idx < 6400; idx += 256) {
    int s = idx >> 6, c = idx & 63;
    tout[(s * 800 + bb) * 64 + c] = (TMP[s][c] - red1[s]) * red2[s] * g2[c] + b2[c];
  }
}

// ---------------------------------------------------------------- K10: mid proj, gated act, out proj, residual/skip
__global__ __launch_bounds__(256) void k10_final(const float* __restrict__ tout,
                                                 const float* __restrict__ x,
                                                 const float* __restrict__ mid_w, const float* __restrict__ mid_b,
                                                 const float* __restrict__ ow, const float* __restrict__ ob,
                                                 float* __restrict__ dout) {
  int lo = blockIdx.x, b = blockIdx.y, tid = threadIdx.x;
  __shared__ float Y[100][64];
  __shared__ float W1[128][65];
  __shared__ float W2[128][65];
  __shared__ float GG[4][64];
  __shared__ float O2[100][130];
  for (int idx = tid; idx < 6400; idx += 256) {
    int no = idx >> 6, c = idx & 63;
    Y[no][c] = tout[(lo * 800 + b * 100 + no) * 64 + c];
  }
  for (int idx = tid; idx < 8192; idx += 256) {
    int o = idx >> 6, c = idx & 63;
    W1[o][c] = mid_w[idx];
    W2[o][c] = ow[idx];
  }
  __syncthreads();
  int o_ = tid & 63, g = tid >> 6;
  float mb1 = mid_b[o_], mb2 = mid_b[64 + o_];
  float ob1 = ob[o_], ob2 = ob[64 + o_];
#pragma unroll 1
  for (int it = 0; it < 25; ++it) {
    int no = it * 4 + g;
    float z1 = mb1, z2 = mb2;
    for (int c = 0; c < 64; ++c) {
      float yv = Y[no][c];
      z1 += W1[o_][c] * yv;
      z2 += W1[64 + o_][c] * yv;
    }
    GG[g][o_] = sigf(z1) * tanhf(z2);
    __syncthreads();
    float w1 = ob1, w2 = ob2;
    for (int c = 0; c < 64; ++c) {
      float gv = GG[g][c];
      w1 += W2[o_][c] * gv;
      w2 += W2[64 + o_][c] * gv;
    }
    O2[no][o_] = w1;
    O2[no][64 + o_] = w2;
    __syncthreads();
  }
  const float invsq2 = 0.7071067811865476f;
  for (int idx = tid; idx < 6400; idx += 256) {
    int c = idx / 100, no = idx - c * 100;
    int oidx = ((b * 64 + c) * 100 + lo) * 100 + no;
    dout[oidx] = (x[oidx] + O2[no][c]) * invsq2;       // residual out
    dout[5120000 + oidx] = O2[no][64 + c];             // skip out
  }
}

// ----------------------------------------------------------------
extern "C" void kernel_launch(void* const* d_in, const int* in_sizes, int n_in,
                              void* d_out, int out_size, void* d_ws, size_t ws_size,
                              hipStream_t stream) {
  const float* x         = (const float*)d_in[0];
  const float* cond_info = (const float*)d_in[1];
  const float* de        = (const float*)d_in[2];
  const float* dp_w      = (const float*)d_in[3];
  const float* dp_b      = (const float*)d_in[4];
  const float* cond_w    = (const float*)d_in[5];
  const float* cond_b    = (const float*)d_in[6];
  const float* mid_w     = (const float*)d_in[7];
  const float* mid_b     = (const float*)d_in[8];
  const float* out_w     = (const float*)d_in[9];
  const float* out_b     = (const float*)d_in[10];
  const float* sa_W      = (const float*)d_in[11];
  const float* sa_a      = (const float*)d_in[12];
  // d_in[13] = sa_GL: unused (adj = softmax(..)+I is strictly positive -> where() is a no-op)
  const float* lstm_Wih  = (const float*)d_in[14];
  const float* lstm_Whh  = (const float*)d_in[15];
  const float* lstm_bih  = (const float*)d_in[16];
  const float* lstm_bhh  = (const float*)d_in[17];
  const float* lin_w     = (const float*)d_in[18];
  const float* lin_b     = (const float*)d_in[19];
  const float* tr_in_w   = (const float*)d_in[20];
  const float* tr_in_b   = (const float*)d_in[21];
  const float* tr_out_w  = (const float*)d_in[22];
  const float* tr_out_b  = (const float*)d_in[23];
  const float* tr_f1w    = (const float*)d_in[24];
  const float* tr_f1b    = (const float*)d_in[25];
  const float* tr_f2w    = (const float*)d_in[26];
  const float* tr_f2b    = (const float*)d_in[27];
  const float* tr_ln1g   = (const float*)d_in[28];
  const float* tr_ln1b   = (const float*)d_in[29];
  const float* tr_ln2g   = (const float*)d_in[30];
  const float* tr_ln2b   = (const float*)d_in[31];

  float* ws   = (float*)d_ws;
  float* SAIN = ws + OFF_SAIN;
  float* H    = ws + OFF_H;
  float* HP   = ws + OFF_HP;
  float* GX   = ws + OFF_GX;
  float* HS   = ws + OFF_HS;    // reuse SAIN region
  float* TIN  = ws + OFF_TIN;   // reuse H region
  float* TOUT = ws + OFF_TOUT;  // reuse HP region
  float* DEMB = ws + OFF_DEMB;
  float* F1   = ws + OFF_F1;
  float* F2   = ws + OFF_F2;
  float* ATT  = ws + OFF_ATT;
  float* dout = (float*)d_out;

  k0_demb<<<1, 512, 0, stream>>>(de, dp_w, dp_b, DEMB);
  k1_sain<<<dim3(100, 8), 256, 0, stream>>>(x, cond_info, cond_w, cond_b, DEMB, SAIN);
  k3_gemm<<<dim3(50, 13), 256, 0, stream>>>(SAIN, sa_W, H);
  k4_f12<<<800, 256, 0, stream>>>(H, sa_a, F1, F2);
  k5_att<<<8, 128, 0, stream>>>(F1, F2, ATT);
  k5b_hprime<<<dim3(100, 8), 256, 0, stream>>>(H, ATT, HP);
  k6_gx<<<800, 256, 0, stream>>>(HP, lstm_Wih, lstm_bih, lstm_bhh, GX);
  k7_lstm<<<100, 256, 0, stream>>>(GX, lstm_Whh, HS);
  k8_y2<<<800, 256, 0, stream>>>(HS, lin_w, lin_b, TIN);
  k9_tr<<<800, 256, 0, stream>>>(TIN, TOUT, tr_in_w, tr_in_b, tr_out_w, tr_out_b,
                                 tr_f1w, tr_f1b, tr_f2w, tr_f2b,
                                 tr_ln1g, tr_ln1b, tr_ln2g, tr_ln2b);
  k10_final<<<dim3(100, 8), 256, 0, stream>>>(TOUT, x, mid_w, mid_b, out_w, out_b, dout);
}

// Round 4
// 3154.095 us; speedup vs baseline: 1.2677x; 1.2677x over previous
//
#include <hip/hip_runtime.h>
#include <math.h>

// Problem constants
#define B_ 8
#define C_ 64
#define L_ 100
#define N_ 100
#define SIDE_ 144
#define DEMB_ 128
#define OUTC_ 6400   // C*L
#define TOPK_ 20
#define G_ 64

// Workspace layout (floats). Peak ~35.93M floats ~= 143.7 MB.
// Reuse: HS<-SAIN, TIN<-H, TOUT<-HP, QKV<-GX, CTX<-HS (lifetimes disjoint).
#define OFF_SAIN 0
#define OFF_H    5120000
#define OFF_HP   10240000
#define OFF_GX   15360000
#define OFF_HS   0
#define OFF_TIN  5120000
#define OFF_TOUT 10240000
#define OFF_QKV  15360000
#define OFF_CTX  0
#define OFF_DEMB 35840000
#define OFF_F1   35840512
#define OFF_F2   35841312
#define OFF_ATT  35842112

__device__ __forceinline__ float sigf(float x) { return 1.f / (1.f + expf(-x)); }

// ---------------------------------------------------------------- K0: diffusion emb
__global__ __launch_bounds__(512) void k0_demb(const float* __restrict__ de,
                                               const float* __restrict__ dpw,
                                               const float* __restrict__ dpb,
                                               float* __restrict__ demb) {
  int tid = threadIdx.x;          // 512 = 8 b * 64 c
  int b = tid >> 6, c = tid & 63;
  float a = dpb[c];
  for (int k = 0; k < DEMB_; ++k) a += de[b * DEMB_ + k] * dpw[c * DEMB_ + k];
  demb[b * 64 + c] = a;
}

// ---------------------------------------------------------------- K1: x + demb + cond proj -> sa_in [b][n][l*64+c]
__global__ __launch_bounds__(256) void k1_sain(const float* __restrict__ x,
                                               const float* __restrict__ ci_g,
                                               const float* __restrict__ cw_g,
                                               const float* __restrict__ cb,
                                               const float* __restrict__ demb,
                                               float* __restrict__ sain) {
  int l = blockIdx.x, b = blockIdx.y, tid = threadIdx.x;
  __shared__ float ci[72][100];   // chunk of cond_info [s][n]
  __shared__ float cw[72][64];    // chunk of cond_w transposed [s][c]
  __shared__ float xt[64][101];   // x tile [c][n], pitch 101 -> conflict-free reads
  float acc[25];
#pragma unroll
  for (int i = 0; i < 25; ++i) acc[i] = 0.f;
  for (int idx = tid; idx < 6400; idx += 256) {
    int c = idx / 100, n = idx - c * 100;
    xt[c][n] = x[((b * C_ + c) * L_ + l) * N_ + n];
  }
  for (int ch = 0; ch < 2; ++ch) {
    int s0 = ch * 72;
    __syncthreads();
    for (int idx = tid; idx < 7200; idx += 256) {
      int s = idx / 100, n = idx - s * 100;
      ci[s][n] = ci_g[((b * SIDE_ + s0 + s) * L_ + l) * N_ + n];
    }
    for (int idx = tid; idx < 4608; idx += 256) {
      int s = idx >> 6, c = idx & 63;
      cw[s][c] = cw_g[c * SIDE_ + s0 + s];
    }
    __syncthreads();
#pragma unroll
    for (int i = 0; i < 25; ++i) {
      int o = i * 256 + tid;
      int n = o >> 6, c = o & 63;
      float a = 0.f;
      for (int s = 0; s < 72; ++s) a += cw[s][c] * ci[s][n];
      acc[i] += a;
    }
  }
#pragma unroll
  for (int i = 0; i < 25; ++i) {
    int o = i * 256 + tid;
    int n = o >> 6, c = o & 63;
    sain[(b * N_ + n) * OUTC_ + l * 64 + c] =
        acc[i] + xt[c][n] + demb[b * 64 + c] + cb[c];
  }
}

// ---------------------------------------------------------------- K3: h = sa_in @ sa_W  (M=800,K=6400,N=6400 fp32)
__global__ __launch_bounds__(256) void k3_gemm(const float* __restrict__ A,
                                               const float* __restrict__ Bm,
                                               float* __restrict__ Cm) {
  __shared__ float As[16][64];    // k-major A tile
  __shared__ float Bs[16][128];
  int bx = blockIdx.x, by = blockIdx.y, tid = threadIdx.x;
  int tx = tid & 15, ty = tid >> 4;
  int row0 = by * 64, col0 = bx * 128;
  float acc[4][8];
#pragma unroll
  for (int i = 0; i < 4; ++i)
#pragma unroll
    for (int j = 0; j < 8; ++j) acc[i][j] = 0.f;
  int am = tid >> 2, ak = (tid & 3) * 4;    // A: 64 rows x 16 k, 1 float4/thread
  int bk = tid >> 4, bj = (tid & 15) * 8;   // B: 16 k x 128 cols, 2 float4/thread
  int arow = row0 + am;
  bool avalid = arow < 800;
  const float* aptr = A + arow * 6400 + ak;
  for (int k0 = 0; k0 < 6400; k0 += 16) {
    float4 av = make_float4(0.f, 0.f, 0.f, 0.f);
    if (avalid) av = *(const float4*)(aptr + k0);
    const float* bp = &Bm[(size_t)(k0 + bk) * 6400 + col0 + bj];
    float4 bv0 = *(const float4*)bp;
    float4 bv1 = *(const float4*)(bp + 4);
    __syncthreads();
    As[ak + 0][am] = av.x; As[ak + 1][am] = av.y;
    As[ak + 2][am] = av.z; As[ak + 3][am] = av.w;
    *(float4*)&Bs[bk][bj] = bv0;
    *(float4*)&Bs[bk][bj + 4] = bv1;
    __syncthreads();
#pragma unroll
    for (int k = 0; k < 16; ++k) {
      float4 a4 = *(const float4*)&As[k][ty * 4];
      float4 b0 = *(const float4*)&Bs[k][tx * 8];
      float4 b1 = *(const float4*)&Bs[k][tx * 8 + 4];
      float ar[4] = {a4.x, a4.y, a4.z, a4.w};
      float br[8] = {b0.x, b0.y, b0.z, b0.w, b1.x, b1.y, b1.z, b1.w};
#pragma unroll
      for (int i = 0; i < 4; ++i)
#pragma unroll
        for (int j = 0; j < 8; ++j) acc[i][j] += ar[i] * br[j];
    }
  }
#pragma unroll
  for (int i = 0; i < 4; ++i) {
    int r = row0 + ty * 4 + i;
    if (r < 800) {
      float4 v0 = make_float4(acc[i][0], acc[i][1], acc[i][2], acc[i][3]);
      float4 v1 = make_float4(acc[i][4], acc[i][5], acc[i][6], acc[i][7]);
      *(float4*)&Cm[r * 6400 + col0 + tx * 8] = v0;
      *(float4*)&Cm[r * 6400 + col0 + tx * 8 + 4] = v1;
    }
  }
}

// ---------------------------------------------------------------- K4: f1/f2 = h @ a1, h @ a2
__global__ __launch_bounds__(256) void k4_f12(const float* __restrict__ h,
                                              const float* __restrict__ sa_a,
                                              float* __restrict__ f1,
                                              float* __restrict__ f2) {
  int row = blockIdx.x, tid = threadIdx.x;
  __shared__ float r1[256], r2[256];
  float a1 = 0.f, a2 = 0.f;
  for (int i = tid; i < 6400; i += 256) {
    float hv = h[row * 6400 + i];
    a1 += hv * sa_a[i];
    a2 += hv * sa_a[6400 + i];
  }
  r1[tid] = a1; r2[tid] = a2;
  __syncthreads();
  for (int s = 128; s > 0; s >>= 1) {
    if (tid < s) { r1[tid] += r1[tid + s]; r2[tid] += r2[tid + s]; }
    __syncthreads();
  }
  if (tid == 0) { f1[row] = r1[0]; f2[row] = r2[0]; }
}

// ---------------------------------------------------------------- K5: e -> top20/col mask -> row softmax -> att
__global__ __launch_bounds__(128) void k5_att(const float* __restrict__ f1,
                                              const float* __restrict__ f2,
                                              float* __restrict__ att) {
  int b = blockIdx.x, tid = threadIdx.x;  // 128 threads
  __shared__ float E[100][101];
  __shared__ float M2[100][101];
  __shared__ float f1s[100], f2s[100];
  if (tid < 100) { f1s[tid] = f1[b * 100 + tid]; f2s[tid] = f2[b * 100 + tid]; }
  __syncthreads();
  for (int idx = tid; idx < 10000; idx += 128) {
    int i = idx / 100, j = idx - i * 100;
    float v = f1s[i] + f2s[j];
    E[i][j] = v > 0.f ? v : 0.01f * v;   // leaky_relu 0.01
  }
  __syncthreads();
  if (tid < 100) {        // per-column top-20 over rows i (ties -> lowest index)
    int j = tid;
    unsigned long long c0 = 0ull, c1 = 0ull;
    for (int it = 0; it < TOPK_; ++it) {
      float best = -1e30f; int bi = 0;
      for (int i = 0; i < 100; ++i) {
        bool used = (i < 64) ? ((c0 >> i) & 1ull) : ((c1 >> (i - 64)) & 1ull);
        float v = E[i][j];
        if (!used && v > best) { best = v; bi = i; }
      }
      if (bi < 64) c0 |= 1ull << bi; else c1 |= 1ull << (bi - 64);
    }
    for (int i = 0; i < 100; ++i) {
      bool sel = (i < 64) ? ((c0 >> i) & 1ull) : ((c1 >> (i - 64)) & 1ull);
      M2[i][j] = sel ? E[i][j] : 0.f;    // multiplicative mask, per source
    }
  }
  __syncthreads();
  if (tid < 100) {        // row softmax over j
    int i = tid;
    float mx = -1e30f;
    for (int j = 0; j < 100; ++j) mx = fmaxf(mx, M2[i][j]);
    float sm = 0.f;
    for (int j = 0; j < 100; ++j) { float e = expf(M2[i][j] - mx); M2[i][j] = e; sm += e; }
    float inv = 1.f / sm;
    for (int j = 0; j < 100; ++j) att[(b * 100 + i) * 100 + j] = M2[i][j] * inv;
  }
}

// ---------------------------------------------------------------- K5b: hp = relu(att @ h)  [b][node][f]
__global__ __launch_bounds__(256) void k5b_hprime(const float* __restrict__ h,
                                                  const float* __restrict__ att,
                                                  float* __restrict__ hp) {
  int ft = blockIdx.x, b = blockIdx.y, tid = threadIdx.x;
  __shared__ float A[100][101];
  for (int idx = tid; idx < 10000; idx += 256)
    A[idx / 100][idx % 100] = att[b * 10000 + idx];
  __syncthreads();
  int cidx = tid & 63, g = tid >> 6;
  int col = ft * 64 + cidx;
  float acc[25];
#pragma unroll
  for (int r = 0; r < 25; ++r) acc[r] = 0.f;
  for (int k = 0; k < 100; ++k) {
    float hv = h[(b * 100 + k) * 6400 + col];
#pragma unroll
    for (int r = 0; r < 25; ++r) acc[r] += A[g * 25 + r][k] * hv;
  }
#pragma unroll
  for (int r = 0; r < 25; ++r) {
    float v = acc[r];
    hp[(b * 100 + (g * 25 + r)) * 6400 + col] = v > 0.f ? v : 0.f;
  }
}

// ---------------------------------------------------------------- K6: LSTM input precompute gx[t][l][j]
__global__ __launch_bounds__(256) void k6_gx(const float* __restrict__ hp,
                                             const float* __restrict__ Wih,
                                             const float* __restrict__ bih,
                                             const float* __restrict__ bhh,
                                             float* __restrict__ gx) {
  int t = blockIdx.x, tid = threadIdx.x;
  int b = t / 100, n2 = t - b * 100;
  __shared__ float inb[100][64];
  for (int idx = tid; idx < 6400; idx += 256) {
    int l = idx >> 6, c = idx & 63;
    inb[l][c] = hp[(b * 100 + l) * 6400 + c * 100 + n2];
  }
  float wr[64];
#pragma unroll
  for (int c = 0; c < 64; ++c) wr[c] = Wih[tid * 64 + c];
  float base = bih[tid] + bhh[tid];
  __syncthreads();
  for (int l = 0; l < 100; ++l) {
    float a = base;
#pragma unroll
    for (int c = 0; c < 64; ++c) a += wr[c] * inb[l][c];
    gx[(t * 100 + l) * 256 + tid] = a;
  }
}

// ---------------------------------------------------------------- K7: LSTM recurrence, 1 block per batch-lane l
__global__ __launch_bounds__(256) void k7_lstm(const float* __restrict__ gx,
                                               const float* __restrict__ Whh,
                                               float* __restrict__ hs) {
  int l = blockIdx.x, j = threadIdx.x;
  __shared__ float hsh[64];
  __shared__ float gl[256];
  float wr[64];
#pragma unroll
  for (int k = 0; k < 64; ++k) wr[k] = Whh[j * 64 + k];
  if (j < 64) hsh[j] = 0.f;
  float c = 0.f;
  __syncthreads();
  float gcur = gx[l * 256 + j];
  for (int t = 0; t < 800; ++t) {
    float gnext = (t < 799) ? gx[((t + 1) * 100 + l) * 256 + j] : 0.f;  // prefetch
    float a = gcur;
#pragma unroll
    for (int k = 0; k < 64; ++k) a += wr[k] * hsh[k];
    gl[j] = a;
    __syncthreads();
    if (j < 64) {
      float ig = sigf(gl[j]);
      float fg = sigf(gl[64 + j]);
      float gg = tanhf(gl[128 + j]);
      float og = sigf(gl[192 + j]);
      c = fg * c + ig * gg;
      float hn = og * tanhf(c);
      hsh[j] = hn;
      hs[(t * 100 + l) * 64 + j] = hn;
    }
    __syncthreads();
    gcur = gnext;
  }
}

// ---------------------------------------------------------------- K8: y2 = silu(hs @ lin_w.T + b) -> tin[s][b][l][c]
__global__ __launch_bounds__(256) void k8_y2(const float* __restrict__ hs,
                                             const float* __restrict__ lin_w,
                                             const float* __restrict__ lin_b,
                                             float* __restrict__ tin) {
  int t = blockIdx.x, tid = threadIdx.x;
  int b = t / 100, n2 = t - b * 100;
  __shared__ float hsl[100][64];
  for (int idx = tid; idx < 6400; idx += 256)
    hsl[idx >> 6][idx & 63] = hs[t * 6400 + idx];
  int c = tid & 63;
  float lw[64];
#pragma unroll
  for (int k = 0; k < 64; ++k) lw[k] = lin_w[c * 64 + k];
  float bias = lin_b[c];
  __syncthreads();
#pragma unroll
  for (int i = 0; i < 25; ++i) {
    int o = i * 256 + tid;
    int l = o >> 6;
    float a = bias;
#pragma unroll
    for (int k = 0; k < 64; ++k) a += lw[k] * hsl[l][k];
    tin[((n2 * 8 + b) * 100 + l) * 64 + c] = a * sigf(a);   // silu
  }
}

// ---------------------------------------------------------------- K9a: QKV projection per bb
// LDS ~76KB -> 2 blocks/CU. quad-output threads: 1 broadcast + 1 b128 + 4 FMA per k.
__global__ __launch_bounds__(256) void k9a_qkv(const float* __restrict__ tin,
                                               const float* __restrict__ in_w,
                                               const float* __restrict__ in_b,
                                               float* __restrict__ qkv) {
  int bb = blockIdx.x;
  int b = bb / 100, l = bb - b * 100;
  int tid = threadIdx.x;
  __shared__ float Xs[100][64];
  __shared__ float Wt[64][196];   // [c][r]; pitch 196: 16B-aligned quads, 8-way write conflict (one-time)
  __shared__ float bs[192];
  for (int idx = tid; idx < 6400; idx += 256) {
    int s = idx >> 6, c = idx & 63;
    Xs[s][c] = tin[((s * 8 + b) * 100 + l) * 64 + c];
  }
  for (int idx = tid; idx < 12288; idx += 256) {
    int r = idx >> 6, c = idx & 63;
    Wt[c][r] = in_w[idx];
  }
  if (tid < 192) bs[tid] = in_b[tid];
  __syncthreads();
  for (int i = 0; i < 19; ++i) {   // 4800 r-quads: s = q/48, rq = (q%48)*4
    int q = i * 256 + tid;
    if (q < 4800) {
      int s = q / 48, rq = (q - s * 48) * 4;
      float a0 = bs[rq], a1 = bs[rq + 1], a2 = bs[rq + 2], a3 = bs[rq + 3];
#pragma unroll
      for (int c = 0; c < 64; ++c) {
        float xv = Xs[s][c];
        float4 w = *(const float4*)&Wt[c][rq];
        a0 += xv * w.x; a1 += xv * w.y; a2 += xv * w.z; a3 += xv * w.w;
      }
      *(float4*)&qkv[(bb * 100 + s) * 192 + rq] = make_float4(a0, a1, a2, a3);
    }
  }
}

// ---------------------------------------------------------------- K9b: attention per (head, bb). LDS ~52KB -> 3/CU
__global__ __launch_bounds__(256) void k9b_attn(const float* __restrict__ qkv,
                                                float* __restrict__ ctx) {
  int h = blockIdx.x, bb = blockIdx.y;
  int tid = threadIdx.x;
  __shared__ float Qh[100][9], Kh[100][9], Vh[100][9];  // pitch 9: conflict-free
  __shared__ float Sc[100][101];
  for (int idx = tid; idx < 800; idx += 256) {
    int s = idx >> 3, e = idx & 7;
    const float* base = &qkv[(bb * 100 + s) * 192 + h * 8 + e];
    Qh[s][e] = base[0];
    Kh[s][e] = base[64];
    Vh[s][e] = base[128];
  }
  __syncthreads();
  for (int idx = tid; idx < 10000; idx += 256) {
    int i = idx / 100, j = idx - i * 100;
    float a = 0.f;
#pragma unroll
    for (int e = 0; e < 8; ++e) a += Qh[i][e] * Kh[j][e];
    Sc[i][j] = a * 0.35355339059327373f;   // 1/sqrt(8)
  }
  __syncthreads();
  if (tid < 100) {   // softmax over keys
    float mx = -1e30f;
    for (int j = 0; j < 100; ++j) mx = fmaxf(mx, Sc[tid][j]);
    float sm = 0.f;
    for (int j = 0; j < 100; ++j) { float e = expf(Sc[tid][j] - mx); Sc[tid][j] = e; sm += e; }
    float inv = 1.f / sm;
    for (int j = 0; j < 100; ++j) Sc[tid][j] *= inv;
  }
  __syncthreads();
  for (int idx = tid; idx < 800; idx += 256) {
    int s = idx >> 3, e = idx & 7;
    float a = 0.f;
    for (int j = 0; j < 100; ++j) a += Sc[s][j] * Vh[j][e];
    ctx[(bb * 100 + s) * 64 + h * 8 + e] = a;
  }
}

// ---------------------------------------------------------------- K9c: outproj+LN1+FF+LN2 per bb. LDS ~73KB -> 2/CU
__global__ __launch_bounds__(256) void k9c_ffn(const float* __restrict__ tin,
                                               const float* __restrict__ ctxg,
                                               float* __restrict__ tout,
                                               const float* __restrict__ ow, const float* __restrict__ ob,
                                               const float* __restrict__ f1w, const float* __restrict__ f1b,
                                               const float* __restrict__ f2w, const float* __restrict__ f2b,
                                               const float* __restrict__ g1, const float* __restrict__ b1,
                                               const float* __restrict__ g2, const float* __restrict__ b2) {
  int bb = blockIdx.x;
  int b = bb / 100, l = bb - b * 100;
  int tid = threadIdx.x;
  __shared__ float T[100][68];   // pitch 68: aligned float4, LN-serial 8-way only
  __shared__ float F[100][68];
  __shared__ float W[64][68];    // shared weight buffer, reloaded per phase
  __shared__ float mu[100], isd[100];
  __shared__ float S1[64], T1[64];
  // phase 0: stage ctx -> F, load owt: W[d][c] = ow[c][d]
  for (int idx = tid; idx < 6400; idx += 256) {
    int s = idx >> 6, c = idx & 63;
    F[s][c] = ctxg[(bb * 100 + s) * 64 + c];
  }
  for (int idx = tid; idx < 4096; idx += 256) {
    int c = idx >> 6, d = idx & 63;
    W[d][c] = ow[idx];
  }
  __syncthreads();
  // phase 1: T = X + ctx@ow^T + ob   (X read once from global)
  for (int i = 0; i < 7; ++i) {
    int q = i * 256 + tid;
    if (q < 1600) {
      int s = q >> 4, c4 = (q & 15) * 4;
      float d0 = 0.f, d1 = 0.f, d2 = 0.f, d3 = 0.f;
#pragma unroll
      for (int d = 0; d < 64; ++d) {
        float cv = F[s][d];
        float4 w = *(const float4*)&W[d][c4];
        d0 += cv * w.x; d1 += cv * w.y; d2 += cv * w.z; d3 += cv * w.w;
      }
      float4 xv = *(const float4*)&tin[((s * 8 + b) * 100 + l) * 64 + c4];
      float4 o;
      o.x = xv.x + ob[c4] + d0;
      o.y = xv.y + ob[c4 + 1] + d1;
      o.z = xv.z + ob[c4 + 2] + d2;
      o.w = xv.w + ob[c4 + 3] + d3;
      *(float4*)&T[s][c4] = o;
    }
  }
  __syncthreads();
  // phase 2: LN1 stats; concurrently load W[c][f] = g1[c]*f1w[f][c]
  if (tid < 100) {
    float m = 0.f;
    for (int c = 0; c < 64; ++c) m += T[tid][c];
    m *= (1.f / 64.f);
    float var = 0.f;
    for (int c = 0; c < 64; ++c) { float d = T[tid][c] - m; var += d * d; }
    mu[tid] = m; isd[tid] = rsqrtf(var * (1.f / 64.f) + 1e-5f);
  }
  for (int idx = tid; idx < 4096; idx += 256) {
    int f = idx >> 6, c = idx & 63;
    W[c][f] = g1[c] * f1w[idx];
  }
  __syncthreads();
  // phase 3: S1[f] = sum_c g1[c] f1w[f][c];  T1[f] = sum_c b1[c] f1w[f][c]
  if (tid < 64) {
    float s1 = 0.f, t1 = 0.f;
    for (int c = 0; c < 64; ++c) {
      s1 += W[c][tid];
      t1 += b1[c] * f1w[tid * 64 + c];
    }
    S1[tid] = s1; T1[tid] = t1;
  }
  __syncthreads();
  // phase 4: F[s][f] = gelu(f1b + isd*(dot - mu*S1) + T1)
  for (int i = 0; i < 7; ++i) {
    int q = i * 256 + tid;
    if (q < 1600) {
      int s = q >> 4, f4 = (q & 15) * 4;
      float d0 = 0.f, d1 = 0.f, d2 = 0.f, d3 = 0.f;
#pragma unroll
      for (int c = 0; c < 64; ++c) {
        float tv = T[s][c];
        float4 w = *(const float4*)&W[c][f4];
        d0 += tv * w.x; d1 += tv * w.y; d2 += tv * w.z; d3 += tv * w.w;
      }
      float m = mu[s], is = isd[s];
      float a0 = f1b[f4]     + is * (d0 - m * S1[f4])     + T1[f4];
      float a1 = f1b[f4 + 1] + is * (d1 - m * S1[f4 + 1]) + T1[f4 + 1];
      float a2 = f1b[f4 + 2] + is * (d2 - m * S1[f4 + 2]) + T1[f4 + 2];
      float a3 = f1b[f4 + 3] + is * (d3 - m * S1[f4 + 3]) + T1[f4 + 3];
      float4 o;
      o.x = 0.5f * a0 * (1.f + erff(a0 * 0.7071067811865475f));
      o.y = 0.5f * a1 * (1.f + erff(a1 * 0.7071067811865475f));
      o.z = 0.5f * a2 * (1.f + erff(a2 * 0.7071067811865475f));
      o.w = 0.5f * a3 * (1.f + erff(a3 * 0.7071067811865475f));
      *(float4*)&F[s][f4] = o;
    }
  }
  __syncthreads();
  // phase 5: load W[f][c] = f2w[c][f]
  for (int idx = tid; idx < 4096; idx += 256) {
    int c = idx >> 6, f = idx & 63;
    W[f][c] = f2w[idx];
  }
  __syncthreads();
  // phase 6: T = xn1 + F@f2w^T + f2b  (in-place per element)
  for (int i = 0; i < 7; ++i) {
    int q = i * 256 + tid;
    if (q < 1600) {
      int s = q >> 4, c4 = (q & 15) * 4;
      float d0 = 0.f, d1 = 0.f, d2 = 0.f, d3 = 0.f;
#pragma unroll
      for (int f = 0; f < 64; ++f) {
        float fv = F[s][f];
        float4 w = *(const float4*)&W[f][c4];
        d0 += fv * w.x; d1 += fv * w.y; d2 += fv * w.z; d3 += fv * w.w;
      }
      float m = mu[s], is = isd[s];
      float4 tv = *(const float4*)&T[s][c4];
      float4 o;
      o.x = (tv.x - m) * is * g1[c4]     + b1[c4]     + f2b[c4]     + d0;
      o.y = (tv.y - m) * is * g1[c4 + 1] + b1[c4 + 1] + f2b[c4 + 1] + d1;
      o.z = (tv.z - m) * is * g1[c4 + 2] + b1[c4 + 2] + f2b[c4 + 2] + d2;
      o.w = (tv.w - m) * is * g1[c4 + 3] + b1[c4 + 3] + f2b[c4 + 3] + d3;
      *(float4*)&T[s][c4] = o;
    }
  }
  __syncthreads();
  // phase 7: LN2 stats
  if (tid < 100) {
    float m = 0.f;
    for (int c = 0; c < 64; ++c) m += T[tid][c];
    m *= (1.f / 64.f);
    float var = 0.f;
    for (int c = 0; c < 64; ++c) { float d = T[tid][c] - m; var += d * d; }
    mu[tid] = m; isd[tid] = rsqrtf(var * (1.f / 64.f) + 1e-5f);
  }
  __syncthreads();
  // phase 8: final write, layout (s*800+bb)*64+c
  for (int idx = tid; idx < 6400; idx += 256) {
    int s = idx >> 6, c = idx & 63;
    tout[(s * 800 + bb) * 64 + c] = (T[s][c] - mu[s]) * isd[s] * g2[c] + b2[c];
  }
}

// ---------------------------------------------------------------- K10: mid proj, gated act, out proj, residual/skip
__global__ __launch_bounds__(256) void k10_final(const float* __restrict__ tout,
                                                 const float* __restrict__ x,
                                                 const float* __restrict__ mid_w, const float* __restrict__ mid_b,
                                                 const float* __restrict__ ow, const float* __restrict__ ob,
                                                 float* __restrict__ dout) {
  int lo = blockIdx.x, b = blockIdx.y, tid = threadIdx.x;
  __shared__ float Y[100][64];
  __shared__ float W1[128][65];
  __shared__ float W2[128][65];
  __shared__ float GG[4][64];
  __shared__ float O2[100][130];
  for (int idx = tid; idx < 6400; idx += 256) {
    int no = idx >> 6, c = idx & 63;
    Y[no][c] = tout[(lo * 800 + b * 100 + no) * 64 + c];
  }
  for (int idx = tid; idx < 8192; idx += 256) {
    int o = idx >> 6, c = idx & 63;
    W1[o][c] = mid_w[idx];
    W2[o][c] = ow[idx];
  }
  __syncthreads();
  int o_ = tid & 63, g = tid >> 6;
  float mb1 = mid_b[o_], mb2 = mid_b[64 + o_];
  float ob1 = ob[o_], ob2 = ob[64 + o_];
#pragma unroll 1
  for (int it = 0; it < 25; ++it) {
    int no = it * 4 + g;
    float z1 = mb1, z2 = mb2;
    for (int c = 0; c < 64; ++c) {
      float yv = Y[no][c];
      z1 += W1[o_][c] * yv;
      z2 += W1[64 + o_][c] * yv;
    }
    GG[g][o_] = sigf(z1) * tanhf(z2);
    __syncthreads();
    float w1 = ob1, w2 = ob2;
    for (int c = 0; c < 64; ++c) {
      float gv = GG[g][c];
      w1 += W2[o_][c] * gv;
      w2 += W2[64 + o_][c] * gv;
    }
    O2[no][o_] = w1;
    O2[no][64 + o_] = w2;
    __syncthreads();
  }
  const float invsq2 = 0.7071067811865476f;
  for (int idx = tid; idx < 6400; idx += 256) {
    int c = idx / 100, no = idx - c * 100;
    int oidx = ((b * 64 + c) * 100 + lo) * 100 + no;
    dout[oidx] = (x[oidx] + O2[no][c]) * invsq2;       // residual out
    dout[5120000 + oidx] = O2[no][64 + c];             // skip out
  }
}

// ----------------------------------------------------------------
extern "C" void kernel_launch(void* const* d_in, const int* in_sizes, int n_in,
                              void* d_out, int out_size, void* d_ws, size_t ws_size,
                              hipStream_t stream) {
  const float* x         = (const float*)d_in[0];
  const float* cond_info = (const float*)d_in[1];
  const float* de        = (const float*)d_in[2];
  const float* dp_w      = (const float*)d_in[3];
  const float* dp_b      = (const float*)d_in[4];
  const float* cond_w    = (const float*)d_in[5];
  const float* cond_b    = (const float*)d_in[6];
  const float* mid_w     = (const float*)d_in[7];
  const float* mid_b     = (const float*)d_in[8];
  const float* out_w     = (const float*)d_in[9];
  const float* out_b     = (const float*)d_in[10];
  const float* sa_W      = (const float*)d_in[11];
  const float* sa_a      = (const float*)d_in[12];
  // d_in[13] = sa_GL: unused (adj = softmax(..)+I strictly positive -> where() no-op)
  const float* lstm_Wih  = (const float*)d_in[14];
  const float* lstm_Whh  = (const float*)d_in[15];
  const float* lstm_bih  = (const float*)d_in[16];
  const float* lstm_bhh  = (const float*)d_in[17];
  const float* lin_w     = (const float*)d_in[18];
  const float* lin_b     = (const float*)d_in[19];
  const float* tr_in_w   = (const float*)d_in[20];
  const float* tr_in_b   = (const float*)d_in[21];
  const float* tr_out_w  = (const float*)d_in[22];
  const float* tr_out_b  = (const float*)d_in[23];
  const float* tr_f1w    = (const float*)d_in[24];
  const float* tr_f1b    = (const float*)d_in[25];
  const float* tr_f2w    = (const float*)d_in[26];
  const float* tr_f2b    = (const float*)d_in[27];
  const float* tr_ln1g   = (const float*)d_in[28];
  const float* tr_ln1b   = (const float*)d_in[29];
  const float* tr_ln2g   = (const float*)d_in[30];
  const float* tr_ln2b   = (const float*)d_in[31];

  float* ws   = (float*)d_ws;
  float* SAIN = ws + OFF_SAIN;
  float* H    = ws + OFF_H;
  float* HP   = ws + OFF_HP;
  float* GX   = ws + OFF_GX;
  float* HS   = ws + OFF_HS;    // reuse SAIN region
  float* TIN  = ws + OFF_TIN;   // reuse H region
  float* TOUT = ws + OFF_TOUT;  // reuse HP region
  float* QKV  = ws + OFF_QKV;   // reuse GX region (dead after k7)
  float* CTX  = ws + OFF_CTX;   // reuse HS region (dead after k8)
  float* DEMB = ws + OFF_DEMB;
  float* F1   = ws + OFF_F1;
  float* F2   = ws + OFF_F2;
  float* ATT  = ws + OFF_ATT;
  float* dout = (float*)d_out;

  k0_demb<<<1, 512, 0, stream>>>(de, dp_w, dp_b, DEMB);
  k1_sain<<<dim3(100, 8), 256, 0, stream>>>(x, cond_info, cond_w, cond_b, DEMB, SAIN);
  k3_gemm<<<dim3(50, 13), 256, 0, stream>>>(SAIN, sa_W, H);
  k4_f12<<<800, 256, 0, stream>>>(H, sa_a, F1, F2);
  k5_att<<<8, 128, 0, stream>>>(F1, F2, ATT);
  k5b_hprime<<<dim3(100, 8), 256, 0, stream>>>(H, ATT, HP);
  k6_gx<<<800, 256, 0, stream>>>(HP, lstm_Wih, lstm_bih, lstm_bhh, GX);
  k7_lstm<<<100, 256, 0, stream>>>(GX, lstm_Whh, HS);
  k8_y2<<<800, 256, 0, stream>>>(HS, lin_w, lin_b, TIN);
  k9a_qkv<<<800, 256, 0, stream>>>(TIN, tr_in_w, tr_in_b, QKV);
  k9b_attn<<<dim3(8, 800), 256, 0, stream>>>(QKV, CTX);
  k9c_ffn<<<800, 256, 0, stream>>>(TIN, CTX, TOUT, tr_out_w, tr_out_b,
                                   tr_f1w, tr_f1b, tr_f2w, tr_f2b,
                                   tr_ln1g, tr_ln1b, tr_ln2g, tr_ln2b);
  k10_final<<<dim3(100, 8), 256, 0, stream>>>(TOUT, x, mid_w, mid_b, out_w, out_b, dout);
}

// Round 5
// 2306.896 us; speedup vs baseline: 1.7333x; 1.3672x over previous
//
#include <hip/hip_runtime.h>
#include <math.h>

// Problem constants
#define B_ 8
#define C_ 64
#define L_ 100
#define N_ 100
#define SIDE_ 144
#define DEMB_ 128
#define OUTC_ 6400   // C*L
#define TOPK_ 20
#define G_ 64

// Workspace layout (floats). Peak ~35.94M floats ~= 143.8 MB (same as proven r3/r4).
// Reuse: HS<-SAIN, TIN<-H, TOUT<-HP, QKV<-GX, CTX<-HS.
// NEW: W_BT (bf16 W^T, 20.48M float-slots) <- GX region (dead until k6);
//      SAIN_BF (bf16 sain, 2.56M float-slots) <- HP region (dead until k5b).
#define OFF_SAIN 0
#define OFF_H    5120000
#define OFF_HP   10240000
#define OFF_GX   15360000
#define OFF_HS   0
#define OFF_TIN  5120000
#define OFF_TOUT 10240000
#define OFF_QKV  15360000
#define OFF_CTX  0
#define OFF_SABF 10240000   // bf16, in HP region
#define OFF_WBT  15360000   // bf16, in GX region
#define OFF_DEMB 35840000
#define OFF_F1   35840512
#define OFF_F2   35841312
#define OFF_ATT  35842112
#define OFF_WA   35922112   // [2][6400] fp32

typedef __attribute__((ext_vector_type(8))) short short8v;
typedef __attribute__((ext_vector_type(4))) unsigned short ushort4v;
typedef __attribute__((ext_vector_type(4))) float f32x4;

__device__ __forceinline__ float sigf(float x) { return 1.f / (1.f + expf(-x)); }
__device__ __forceinline__ unsigned short f2bf(float f) {   // RNE fp32->bf16
  unsigned int u = __float_as_uint(f);
  u += 0x7fffu + ((u >> 16) & 1u);
  return (unsigned short)(u >> 16);
}

// ---------------------------------------------------------------- K0: diffusion emb
__global__ __launch_bounds__(512) void k0_demb(const float* __restrict__ de,
                                               const float* __restrict__ dpw,
                                               const float* __restrict__ dpb,
                                               float* __restrict__ demb) {
  int tid = threadIdx.x;          // 512 = 8 b * 64 c
  int b = tid >> 6, c = tid & 63;
  float a = dpb[c];
  for (int k = 0; k < DEMB_; ++k) a += de[b * DEMB_ + k] * dpw[c * DEMB_ + k];
  demb[b * 64 + c] = a;
}

// ---------------------------------------------------------------- K1: x + demb + cond proj -> sa_in [b][n][l*64+c]
__global__ __launch_bounds__(256) void k1_sain(const float* __restrict__ x,
                                               const float* __restrict__ ci_g,
                                               const float* __restrict__ cw_g,
                                               const float* __restrict__ cb,
                                               const float* __restrict__ demb,
                                               float* __restrict__ sain) {
  int l = blockIdx.x, b = blockIdx.y, tid = threadIdx.x;
  __shared__ float ci[72][100];
  __shared__ float cw[72][64];
  __shared__ float xt[64][101];
  float acc[25];
#pragma unroll
  for (int i = 0; i < 25; ++i) acc[i] = 0.f;
  for (int idx = tid; idx < 6400; idx += 256) {
    int c = idx / 100, n = idx - c * 100;
    xt[c][n] = x[((b * C_ + c) * L_ + l) * N_ + n];
  }
  for (int ch = 0; ch < 2; ++ch) {
    int s0 = ch * 72;
    __syncthreads();
    for (int idx = tid; idx < 7200; idx += 256) {
      int s = idx / 100, n = idx - s * 100;
      ci[s][n] = ci_g[((b * SIDE_ + s0 + s) * L_ + l) * N_ + n];
    }
    for (int idx = tid; idx < 4608; idx += 256) {
      int s = idx >> 6, c = idx & 63;
      cw[s][c] = cw_g[c * SIDE_ + s0 + s];
    }
    __syncthreads();
#pragma unroll
    for (int i = 0; i < 25; ++i) {
      int o = i * 256 + tid;
      int n = o >> 6, c = o & 63;
      float a = 0.f;
      for (int s = 0; s < 72; ++s) a += cw[s][c] * ci[s][n];
      acc[i] += a;
    }
  }
#pragma unroll
  for (int i = 0; i < 25; ++i) {
    int o = i * 256 + tid;
    int n = o >> 6, c = o & 63;
    sain[(b * N_ + n) * OUTC_ + l * 64 + c] =
        acc[i] + xt[c][n] + demb[b * 64 + c] + cb[c];
  }
}

// ---------------------------------------------------------------- KCA: sain fp32 -> bf16 (same layout)
__global__ __launch_bounds__(256) void kconv_a(const float* __restrict__ in,
                                               unsigned short* __restrict__ out) {
  int i = blockIdx.x * 256 + threadIdx.x;   // 1,280,000 quads exactly
  float4 v = *(const float4*)&in[i * 4];
  ushort4v o;
  o.x = f2bf(v.x); o.y = f2bf(v.y); o.z = f2bf(v.z); o.w = f2bf(v.w);
  *(ushort4v*)&out[i * 4] = o;
}

// ---------------------------------------------------------------- KCW: W[k][n] fp32 -> W_BT[n][k] bf16 (tiled transpose)
__global__ __launch_bounds__(256) void kconv_w(const float* __restrict__ W,
                                               unsigned short* __restrict__ Bt) {
  __shared__ unsigned short Tl[64 * 72];   // [n][k] pitch 72
  int k0 = blockIdx.x * 64, n0 = blockIdx.y * 64, tid = threadIdx.x;
#pragma unroll
  for (int i = 0; i < 4; ++i) {            // 1024 float4 quads
    int q = i * 256 + tid;
    int ki = q >> 4, nj = (q & 15) * 4;
    float4 w = *(const float4*)&W[(size_t)(k0 + ki) * 6400 + n0 + nj];
    Tl[(nj + 0) * 72 + ki] = f2bf(w.x);
    Tl[(nj + 1) * 72 + ki] = f2bf(w.y);
    Tl[(nj + 2) * 72 + ki] = f2bf(w.z);
    Tl[(nj + 3) * 72 + ki] = f2bf(w.w);
  }
  __syncthreads();
#pragma unroll
  for (int i = 0; i < 2; ++i) {            // 512 ushort8 chunks out
    int c = i * 256 + tid;
    int n = c >> 3, koff = (c & 7) * 8;
    *(short8v*)&Bt[(size_t)(n0 + n) * 6400 + k0 + koff] =
        *(const short8v*)&Tl[n * 72 + koff];
  }
}

// ---------------------------------------------------------------- KWA: wa[0][k]=sum_n W[k][n]a1[n]; wa[1][k]=..a2
__global__ __launch_bounds__(256) void kwa(const float* __restrict__ W,
                                           const float* __restrict__ sa_a,
                                           float* __restrict__ wa) {
  int w = threadIdx.x >> 6, lane = threadIdx.x & 63;
  int row = blockIdx.x * 4 + w;
  const float* wr = W + (size_t)row * 6400;
  float s1 = 0.f, s2 = 0.f;
  for (int j = lane; j < 6400; j += 64) {
    float wv = wr[j];
    s1 += wv * sa_a[j];
    s2 += wv * sa_a[6400 + j];
  }
#pragma unroll
  for (int off = 32; off > 0; off >>= 1) {
    s1 += __shfl_down(s1, off, 64);
    s2 += __shfl_down(s2, off, 64);
  }
  if (lane == 0) { wa[row] = s1; wa[6400 + row] = s2; }
}

// ---------------------------------------------------------------- K3: h = sain @ W via bf16 MFMA
// BM=80, BN=128, BK=64; 4 waves; wave owns 80x32 (5x2 frags of 16x16).
// A frag: lane: row=l&15, k=(l>>4)*8+e (8 consecutive bf16). B frag from W_BT rows likewise.
// C/D (m89-verified): col=lane&15, row=(lane>>4)*4+reg.
#define PA 72
#define PB 72
__global__ __launch_bounds__(256) void k3_mfma(const unsigned short* __restrict__ Abf,
                                               const unsigned short* __restrict__ Bt,
                                               float* __restrict__ H) {
  __shared__ unsigned short As[80 * PA];
  __shared__ unsigned short Bs[128 * PB];
  int bx = blockIdx.x, by = blockIdx.y, tid = threadIdx.x;
  int w = tid >> 6, lane = tid & 63;
  int lo = lane & 15, hi = lane >> 4;
  int row0 = by * 80, col0 = bx * 128;
  f32x4 acc[5][2];
#pragma unroll
  for (int i = 0; i < 5; ++i)
#pragma unroll
    for (int j = 0; j < 2; ++j) acc[i][j] = (f32x4){0.f, 0.f, 0.f, 0.f};

  int ar0 = tid >> 3, ao0 = (tid & 7) * 8;               // A chunk ids tid, tid+256, tid+512
  int ar1 = (tid + 256) >> 3, ao1 = ((tid + 256) & 7) * 8;
  int ar2 = (tid + 512) >> 3, ao2 = ((tid + 512) & 7) * 8;
  for (int k0 = 0; k0 < 6400; k0 += 64) {
    short8v ra0, ra1, ra2, rb0, rb1, rb2, rb3;
    ra0 = *(const short8v*)&Abf[(size_t)(row0 + ar0) * 6400 + k0 + ao0];
    ra1 = *(const short8v*)&Abf[(size_t)(row0 + ar1) * 6400 + k0 + ao1];
    if (tid < 128) ra2 = *(const short8v*)&Abf[(size_t)(row0 + ar2) * 6400 + k0 + ao2];
#pragma unroll
    for (int i = 0; i < 4; ++i) {
      int c = i * 256 + tid;
      int r = c >> 3, off = (c & 7) * 8;
      short8v v = *(const short8v*)&Bt[(size_t)(col0 + r) * 6400 + k0 + off];
      if (i == 0) rb0 = v; else if (i == 1) rb1 = v; else if (i == 2) rb2 = v; else rb3 = v;
    }
    __syncthreads();
    *(short8v*)&As[ar0 * PA + ao0] = ra0;
    *(short8v*)&As[ar1 * PA + ao1] = ra1;
    if (tid < 128) *(short8v*)&As[ar2 * PA + ao2] = ra2;
#pragma unroll
    for (int i = 0; i < 4; ++i) {
      int c = i * 256 + tid;
      int r = c >> 3, off = (c & 7) * 8;
      short8v v = (i == 0) ? rb0 : (i == 1) ? rb1 : (i == 2) ? rb2 : rb3;
      *(short8v*)&Bs[r * PB + off] = v;
    }
    __syncthreads();
#pragma unroll
    for (int kk = 0; kk < 64; kk += 32) {
      short8v aF[5], bF[2];
#pragma unroll
      for (int fr = 0; fr < 5; ++fr)
        aF[fr] = *(const short8v*)&As[(lo + 16 * fr) * PA + kk + hi * 8];
#pragma unroll
      for (int fc = 0; fc < 2; ++fc)
        bF[fc] = *(const short8v*)&Bs[(w * 32 + fc * 16 + lo) * PB + kk + hi * 8];
#pragma unroll
      for (int fr = 0; fr < 5; ++fr)
#pragma unroll
        for (int fc = 0; fc < 2; ++fc)
          acc[fr][fc] = __builtin_amdgcn_mfma_f32_16x16x32_bf16(aF[fr], bF[fc], acc[fr][fc], 0, 0, 0);
    }
    __syncthreads();
  }
#pragma unroll
  for (int fr = 0; fr < 5; ++fr)
#pragma unroll
    for (int fc = 0; fc < 2; ++fc) {
      int col = col0 + w * 32 + fc * 16 + lo;
#pragma unroll
      for (int r = 0; r < 4; ++r) {
        int row = row0 + fr * 16 + hi * 4 + r;
        H[(size_t)row * 6400 + col] = acc[fr][fc][r];
      }
    }
}

// ---------------------------------------------------------------- K4: f1/f2 = sain @ wa (exact fp32; == h@a by associativity)
__global__ __launch_bounds__(256) void k4_f12(const float* __restrict__ sain,
                                              const float* __restrict__ wa,
                                              float* __restrict__ f1,
                                              float* __restrict__ f2) {
  int row = blockIdx.x, tid = threadIdx.x;
  __shared__ float r1[256], r2[256];
  float a1 = 0.f, a2 = 0.f;
  for (int i = tid; i < 6400; i += 256) {
    float hv = sain[row * 6400 + i];
    a1 += hv * wa[i];
    a2 += hv * wa[6400 + i];
  }
  r1[tid] = a1; r2[tid] = a2;
  __syncthreads();
  for (int s = 128; s > 0; s >>= 1) {
    if (tid < s) { r1[tid] += r1[tid + s]; r2[tid] += r2[tid + s]; }
    __syncthreads();
  }
  if (tid == 0) { f1[row] = r1[0]; f2[row] = r2[0]; }
}

// ---------------------------------------------------------------- K5: e -> top20/col mask -> row softmax -> att
__global__ __launch_bounds__(128) void k5_att(const float* __restrict__ f1,
                                              const float* __restrict__ f2,
                                              float* __restrict__ att) {
  int b = blockIdx.x, tid = threadIdx.x;
  __shared__ float E[100][101];
  __shared__ float M2[100][101];
  __shared__ float f1s[100], f2s[100];
  if (tid < 100) { f1s[tid] = f1[b * 100 + tid]; f2s[tid] = f2[b * 100 + tid]; }
  __syncthreads();
  for (int idx = tid; idx < 10000; idx += 128) {
    int i = idx / 100, j = idx - i * 100;
    float v = f1s[i] + f2s[j];
    E[i][j] = v > 0.f ? v : 0.01f * v;
  }
  __syncthreads();
  if (tid < 100) {        // per-column top-20 over rows i (ties -> lowest index)
    int j = tid;
    unsigned long long c0 = 0ull, c1 = 0ull;
    for (int it = 0; it < TOPK_; ++it) {
      float best = -1e30f; int bi = 0;
      for (int i = 0; i < 100; ++i) {
        bool used = (i < 64) ? ((c0 >> i) & 1ull) : ((c1 >> (i - 64)) & 1ull);
        float v = E[i][j];
        if (!used && v > best) { best = v; bi = i; }
      }
      if (bi < 64) c0 |= 1ull << bi; else c1 |= 1ull << (bi - 64);
    }
    for (int i = 0; i < 100; ++i) {
      bool sel = (i < 64) ? ((c0 >> i) & 1ull) : ((c1 >> (i - 64)) & 1ull);
      M2[i][j] = sel ? E[i][j] : 0.f;
    }
  }
  __syncthreads();
  if (tid < 100) {        // row softmax over j
    int i = tid;
    float mx = -1e30f;
    for (int j = 0; j < 100; ++j) mx = fmaxf(mx, M2[i][j]);
    float sm = 0.f;
    for (int j = 0; j < 100; ++j) { float e = expf(M2[i][j] - mx); M2[i][j] = e; sm += e; }
    float inv = 1.f / sm;
    for (int j = 0; j < 100; ++j) att[(b * 100 + i) * 100 + j] = M2[i][j] * inv;
  }
}

// ---------------------------------------------------------------- K5b: hp = relu(att @ h)
__global__ __launch_bounds__(256) void k5b_hprime(const float* __restrict__ h,
                                                  const float* __restrict__ att,
                                                  float* __restrict__ hp) {
  int ft = blockIdx.x, b = blockIdx.y, tid = threadIdx.x;
  __shared__ float A[100][101];
  for (int idx = tid; idx < 10000; idx += 256)
    A[idx / 100][idx % 100] = att[b * 10000 + idx];
  __syncthreads();
  int cidx = tid & 63, g = tid >> 6;
  int col = ft * 64 + cidx;
  float acc[25];
#pragma unroll
  for (int r = 0; r < 25; ++r) acc[r] = 0.f;
  for (int k = 0; k < 100; ++k) {
    float hv = h[(b * 100 + k) * 6400 + col];
#pragma unroll
    for (int r = 0; r < 25; ++r) acc[r] += A[g * 25 + r][k] * hv;
  }
#pragma unroll
  for (int r = 0; r < 25; ++r) {
    float v = acc[r];
    hp[(b * 100 + (g * 25 + r)) * 6400 + col] = v > 0.f ? v : 0.f;
  }
}

// ---------------------------------------------------------------- K6: LSTM input precompute gx[t][l][j]
__global__ __launch_bounds__(256) void k6_gx(const float* __restrict__ hp,
                                             const float* __restrict__ Wih,
                                             const float* __restrict__ bih,
                                             const float* __restrict__ bhh,
                                             float* __restrict__ gx) {
  int t = blockIdx.x, tid = threadIdx.x;
  int b = t / 100, n2 = t - b * 100;
  __shared__ float inb[100][64];
  for (int idx = tid; idx < 6400; idx += 256) {
    int l = idx >> 6, c = idx & 63;
    inb[l][c] = hp[(b * 100 + l) * 6400 + c * 100 + n2];
  }
  float wr[64];
#pragma unroll
  for (int c = 0; c < 64; ++c) wr[c] = Wih[tid * 64 + c];
  float base = bih[tid] + bhh[tid];
  __syncthreads();
  for (int l = 0; l < 100; ++l) {
    float a = base;
#pragma unroll
    for (int c = 0; c < 64; ++c) a += wr[c] * inb[l][c];
    gx[(t * 100 + l) * 256 + tid] = a;
  }
}

// ---------------------------------------------------------------- K7: LSTM recurrence
__global__ __launch_bounds__(256) void k7_lstm(const float* __restrict__ gx,
                                               const float* __restrict__ Whh,
                                               float* __restrict__ hs) {
  int l = blockIdx.x, j = threadIdx.x;
  __shared__ float hsh[64];
  __shared__ float gl[256];
  float wr[64];
#pragma unroll
  for (int k = 0; k < 64; ++k) wr[k] = Whh[j * 64 + k];
  if (j < 64) hsh[j] = 0.f;
  float c = 0.f;
  __syncthreads();
  float gcur = gx[l * 256 + j];
  for (int t = 0; t < 800; ++t) {
    float gnext = (t < 799) ? gx[((t + 1) * 100 + l) * 256 + j] : 0.f;
    float a = gcur;
#pragma unroll
    for (int k = 0; k < 64; ++k) a += wr[k] * hsh[k];
    gl[j] = a;
    __syncthreads();
    if (j < 64) {
      float ig = sigf(gl[j]);
      float fg = sigf(gl[64 + j]);
      float gg = tanhf(gl[128 + j]);
      float og = sigf(gl[192 + j]);
      c = fg * c + ig * gg;
      float hn = og * tanhf(c);
      hsh[j] = hn;
      hs[(t * 100 + l) * 64 + j] = hn;
    }
    __syncthreads();
    gcur = gnext;
  }
}

// ---------------------------------------------------------------- K8: y2 = silu(hs @ lin_w.T + b) -> tin
__global__ __launch_bounds__(256) void k8_y2(const float* __restrict__ hs,
                                             const float* __restrict__ lin_w,
                                             const float* __restrict__ lin_b,
                                             float* __restrict__ tin) {
  int t = blockIdx.x, tid = threadIdx.x;
  int b = t / 100, n2 = t - b * 100;
  __shared__ float hsl[100][64];
  for (int idx = tid; idx < 6400; idx += 256)
    hsl[idx >> 6][idx & 63] = hs[t * 6400 + idx];
  int c = tid & 63;
  float lw[64];
#pragma unroll
  for (int k = 0; k < 64; ++k) lw[k] = lin_w[c * 64 + k];
  float bias = lin_b[c];
  __syncthreads();
#pragma unroll
  for (int i = 0; i < 25; ++i) {
    int o = i * 256 + tid;
    int l = o >> 6;
    float a = bias;
#pragma unroll
    for (int k = 0; k < 64; ++k) a += lw[k] * hsl[l][k];
    tin[((n2 * 8 + b) * 100 + l) * 64 + c] = a * sigf(a);
  }
}

// ---------------------------------------------------------------- K9a: QKV projection per bb
__global__ __launch_bounds__(256) void k9a_qkv(const float* __restrict__ tin,
                                               const float* __restrict__ in_w,
                                               const float* __restrict__ in_b,
                                               float* __restrict__ qkv) {
  int bb = blockIdx.x;
  int b = bb / 100, l = bb - b * 100;
  int tid = threadIdx.x;
  __shared__ float Xs[100][64];
  __shared__ float Wt[64][196];
  __shared__ float bs[192];
  for (int idx = tid; idx < 6400; idx += 256) {
    int s = idx >> 6, c = idx & 63;
    Xs[s][c] = tin[((s * 8 + b) * 100 + l) * 64 + c];
  }
  for (int idx = tid; idx < 12288; idx += 256) {
    int r = idx >> 6, c = idx & 63;
    Wt[c][r] = in_w[idx];
  }
  if (tid < 192) bs[tid] = in_b[tid];
  __syncthreads();
  for (int i = 0; i < 19; ++i) {
    int q = i * 256 + tid;
    if (q < 4800) {
      int s = q / 48, rq = (q - s * 48) * 4;
      float a0 = bs[rq], a1 = bs[rq + 1], a2 = bs[rq + 2], a3 = bs[rq + 3];
#pragma unroll
      for (int c = 0; c < 64; ++c) {
        float xv = Xs[s][c];
        float4 w = *(const float4*)&Wt[c][rq];
        a0 += xv * w.x; a1 += xv * w.y; a2 += xv * w.z; a3 += xv * w.w;
      }
      *(float4*)&qkv[(bb * 100 + s) * 192 + rq] = make_float4(a0, a1, a2, a3);
    }
  }
}

// ---------------------------------------------------------------- K9b: attention per (head, bb)
__global__ __launch_bounds__(256) void k9b_attn(const float* __restrict__ qkv,
                                                float* __restrict__ ctx) {
  int h = blockIdx.x, bb = blockIdx.y;
  int tid = threadIdx.x;
  __shared__ float Qh[100][9], Kh[100][9], Vh[100][9];
  __shared__ float Sc[100][101];
  for (int idx = tid; idx < 800; idx += 256) {
    int s = idx >> 3, e = idx & 7;
    const float* base = &qkv[(bb * 100 + s) * 192 + h * 8 + e];
    Qh[s][e] = base[0];
    Kh[s][e] = base[64];
    Vh[s][e] = base[128];
  }
  __syncthreads();
  for (int idx = tid; idx < 10000; idx += 256) {
    int i = idx / 100, j = idx - i * 100;
    float a = 0.f;
#pragma unroll
    for (int e = 0; e < 8; ++e) a += Qh[i][e] * Kh[j][e];
    Sc[i][j] = a * 0.35355339059327373f;
  }
  __syncthreads();
  if (tid < 100) {
    float mx = -1e30f;
    for (int j = 0; j < 100; ++j) mx = fmaxf(mx, Sc[tid][j]);
    float sm = 0.f;
    for (int j = 0; j < 100; ++j) { float e = expf(Sc[tid][j] - mx); Sc[tid][j] = e; sm += e; }
    float inv = 1.f / sm;
    for (int j = 0; j < 100; ++j) Sc[tid][j] *= inv;
  }
  __syncthreads();
  for (int idx = tid; idx < 800; idx += 256) {
    int s = idx >> 3, e = idx & 7;
    float a = 0.f;
    for (int j = 0; j < 100; ++j) a += Sc[s][j] * Vh[j][e];
    ctx[(bb * 100 + s) * 64 + h * 8 + e] = a;
  }
}

// ---------------------------------------------------------------- K9c: outproj+LN1+FF+LN2 per bb
__global__ __launch_bounds__(256) void k9c_ffn(const float* __restrict__ tin,
                                               const float* __restrict__ ctxg,
                                               float* __restrict__ tout,
                                               const float* __restrict__ ow, const float* __restrict__ ob,
                                               const float* __restrict__ f1w, const float* __restrict__ f1b,
                                               const float* __restrict__ f2w, const float* __restrict__ f2b,
                                               const float* __restrict__ g1, const float* __restrict__ b1,
                                               const float* __restrict__ g2, const float* __restrict__ b2) {
  int bb = blockIdx.x;
  int b = bb / 100, l = bb - b * 100;
  int tid = threadIdx.x;
  __shared__ float T[100][68];
  __shared__ float F[100][68];
  __shared__ float W[64][68];
  __shared__ float mu[100], isd[100];
  __shared__ float S1[64], T1[64];
  for (int idx = tid; idx < 6400; idx += 256) {
    int s = idx >> 6, c = idx & 63;
    F[s][c] = ctxg[(bb * 100 + s) * 64 + c];
  }
  for (int idx = tid; idx < 4096; idx += 256) {
    int c = idx >> 6, d = idx & 63;
    W[d][c] = ow[idx];
  }
  __syncthreads();
  for (int i = 0; i < 7; ++i) {
    int q = i * 256 + tid;
    if (q < 1600) {
      int s = q >> 4, c4 = (q & 15) * 4;
      float d0 = 0.f, d1 = 0.f, d2 = 0.f, d3 = 0.f;
#pragma unroll
      for (int d = 0; d < 64; ++d) {
        float cv = F[s][d];
        float4 w = *(const float4*)&W[d][c4];
        d0 += cv * w.x; d1 += cv * w.y; d2 += cv * w.z; d3 += cv * w.w;
      }
      float4 xv = *(const float4*)&tin[((s * 8 + b) * 100 + l) * 64 + c4];
      float4 o;
      o.x = xv.x + ob[c4] + d0;
      o.y = xv.y + ob[c4 + 1] + d1;
      o.z = xv.z + ob[c4 + 2] + d2;
      o.w = xv.w + ob[c4 + 3] + d3;
      *(float4*)&T[s][c4] = o;
    }
  }
  __syncthreads();
  if (tid < 100) {
    float m = 0.f;
    for (int c = 0; c < 64; ++c) m += T[tid][c];
    m *= (1.f / 64.f);
    float var = 0.f;
    for (int c = 0; c < 64; ++c) { float d = T[tid][c] - m; var += d * d; }
    mu[tid] = m; isd[tid] = rsqrtf(var * (1.f / 64.f) + 1e-5f);
  }
  for (int idx = tid; idx < 4096; idx += 256) {
    int f = idx >> 6, c = idx & 63;
    W[c][f] = g1[c] * f1w[idx];
  }
  __syncthreads();
  if (tid < 64) {
    float s1 = 0.f, t1 = 0.f;
    for (int c = 0; c < 64; ++c) {
      s1 += W[c][tid];
      t1 += b1[c] * f1w[tid * 64 + c];
    }
    S1[tid] = s1; T1[tid] = t1;
  }
  __syncthreads();
  for (int i = 0; i < 7; ++i) {
    int q = i * 256 + tid;
    if (q < 1600) {
      int s = q >> 4, f4 = (q & 15) * 4;
      float d0 = 0.f, d1 = 0.f, d2 = 0.f, d3 = 0.f;
#pragma unroll
      for (int c = 0; c < 64; ++c) {
        float tv = T[s][c];
        float4 w = *(const float4*)&W[c][f4];
        d0 += tv * w.x; d1 += tv * w.y; d2 += tv * w.z; d3 += tv * w.w;
      }
      float m = mu[s], is = isd[s];
      float a0 = f1b[f4]     + is * (d0 - m * S1[f4])     + T1[f4];
      float a1 = f1b[f4 + 1] + is * (d1 - m * S1[f4 + 1]) + T1[f4 + 1];
      float a2 = f1b[f4 + 2] + is * (d2 - m * S1[f4 + 2]) + T1[f4 + 2];
      float a3 = f1b[f4 + 3] + is * (d3 - m * S1[f4 + 3]) + T1[f4 + 3];
      float4 o;
      o.x = 0.5f * a0 * (1.f + erff(a0 * 0.7071067811865475f));
      o.y = 0.5f * a1 * (1.f + erff(a1 * 0.7071067811865475f));
      o.z = 0.5f * a2 * (1.f + erff(a2 * 0.7071067811865475f));
      o.w = 0.5f * a3 * (1.f + erff(a3 * 0.7071067811865475f));
      *(float4*)&F[s][f4] = o;
    }
  }
  __syncthreads();
  for (int idx = tid; idx < 4096; idx += 256) {
    int c = idx >> 6, f = idx & 63;
    W[f][c] = f2w[idx];
  }
  __syncthreads();
  for (int i = 0; i < 7; ++i) {
    int q = i * 256 + tid;
    if (q < 1600) {
      int s = q >> 4, c4 = (q & 15) * 4;
      float d0 = 0.f, d1 = 0.f, d2 = 0.f, d3 = 0.f;
#pragma unroll
      for (int f = 0; f < 64; ++f) {
        float fv = F[s][f];
        float4 w = *(const float4*)&W[f][c4];
        d0 += fv * w.x; d1 += fv * w.y; d2 += fv * w.z; d3 += fv * w.w;
      }
      float m = mu[s], is = isd[s];
      float4 tv = *(const float4*)&T[s][c4];
      float4 o;
      o.x = (tv.x - m) * is * g1[c4]     + b1[c4]     + f2b[c4]     + d0;
      o.y = (tv.y - m) * is * g1[c4 + 1] + b1[c4 + 1] + f2b[c4 + 1] + d1;
      o.z = (tv.z - m) * is * g1[c4 + 2] + b1[c4 + 2] + f2b[c4 + 2] + d2;
      o.w = (tv.w - m) * is * g1[c4 + 3] + b1[c4 + 3] + f2b[c4 + 3] + d3;
      *(float4*)&T[s][c4] = o;
    }
  }
  __syncthreads();
  if (tid < 100) {
    float m = 0.f;
    for (int c = 0; c < 64; ++c) m += T[tid][c];
    m *= (1.f / 64.f);
    float var = 0.f;
    for (int c = 0; c < 64; ++c) { float d = T[tid][c] - m; var += d * d; }
    mu[tid] = m; isd[tid] = rsqrtf(var * (1.f / 64.f) + 1e-5f);
  }
  __syncthreads();
  for (int idx = tid; idx < 6400; idx += 256) {
    int s = idx >> 6, c = idx & 63;
    tout[(s * 800 + bb) * 64 + c] = (T[s][c] - mu[s]) * isd[s] * g2[c] + b2[c];
  }
}

// ---------------------------------------------------------------- K10: mid proj, gated act, out proj, residual/skip
__global__ __launch_bounds__(256) void k10_final(const float* __restrict__ tout,
                                                 const float* __restrict__ x,
                                                 const float* __restrict__ mid_w, const float* __restrict__ mid_b,
                                                 const float* __restrict__ ow, const float* __restrict__ ob,
                                                 float* __restrict__ dout) {
  int lo = blockIdx.x, b = blockIdx.y, tid = threadIdx.x;
  __shared__ float Y[100][64];
  __shared__ float W1[128][65];
  __shared__ float W2[128][65];
  __shared__ float GG[4][64];
  __shared__ float O2[100][130];
  for (int idx = tid; idx < 6400; idx += 256) {
    int no = idx >> 6, c = idx & 63;
    Y[no][c] = tout[(lo * 800 + b * 100 + no) * 64 + c];
  }
  for (int idx = tid; idx < 8192; idx += 256) {
    int o = idx >> 6, c = idx & 63;
    W1[o][c] = mid_w[idx];
    W2[o][c] = ow[idx];
  }
  __syncthreads();
  int o_ = tid & 63, g = tid >> 6;
  float mb1 = mid_b[o_], mb2 = mid_b[64 + o_];
  float ob1 = ob[o_], ob2 = ob[64 + o_];
#pragma unroll 1
  for (int it = 0; it < 25; ++it) {
    int no = it * 4 + g;
    float z1 = mb1, z2 = mb2;
    for (int c = 0; c < 64; ++c) {
      float yv = Y[no][c];
      z1 += W1[o_][c] * yv;
      z2 += W1[64 + o_][c] * yv;
    }
    GG[g][o_] = sigf(z1) * tanhf(z2);
    __syncthreads();
    float w1 = ob1, w2 = ob2;
    for (int c = 0; c < 64; ++c) {
      float gv = GG[g][c];
      w1 += W2[o_][c] * gv;
      w2 += W2[64 + o_][c] * gv;
    }
    O2[no][o_] = w1;
    O2[no][64 + o_] = w2;
    __syncthreads();
  }
  const float invsq2 = 0.7071067811865476f;
  for (int idx = tid; idx < 6400; idx += 256) {
    int c = idx / 100, no = idx - c * 100;
    int oidx = ((b * 64 + c) * 100 + lo) * 100 + no;
    dout[oidx] = (x[oidx] + O2[no][c]) * invsq2;
    dout[5120000 + oidx] = O2[no][64 + c];
  }
}

// ----------------------------------------------------------------
extern "C" void kernel_launch(void* const* d_in, const int* in_sizes, int n_in,
                              void* d_out, int out_size, void* d_ws, size_t ws_size,
                              hipStream_t stream) {
  const float* x         = (const float*)d_in[0];
  const float* cond_info = (const float*)d_in[1];
  const float* de        = (const float*)d_in[2];
  const float* dp_w      = (const float*)d_in[3];
  const float* dp_b      = (const float*)d_in[4];
  const float* cond_w    = (const float*)d_in[5];
  const float* cond_b    = (const float*)d_in[6];
  const float* mid_w     = (const float*)d_in[7];
  const float* mid_b     = (const float*)d_in[8];
  const float* out_w     = (const float*)d_in[9];
  const float* out_b     = (const float*)d_in[10];
  const float* sa_W      = (const float*)d_in[11];
  const float* sa_a      = (const float*)d_in[12];
  // d_in[13] = sa_GL: unused (adj = softmax(..)+I strictly positive -> where() no-op)
  const float* lstm_Wih  = (const float*)d_in[14];
  const float* lstm_Whh  = (const float*)d_in[15];
  const float* lstm_bih  = (const float*)d_in[16];
  const float* lstm_bhh  = (const float*)d_in[17];
  const float* lin_w     = (const float*)d_in[18];
  const float* lin_b     = (const float*)d_in[19];
  const float* tr_in_w   = (const float*)d_in[20];
  const float* tr_in_b   = (const float*)d_in[21];
  const float* tr_out_w  = (const float*)d_in[22];
  const float* tr_out_b  = (const float*)d_in[23];
  const float* tr_f1w    = (const float*)d_in[24];
  const float* tr_f1b    = (const float*)d_in[25];
  const float* tr_f2w    = (const float*)d_in[26];
  const float* tr_f2b    = (const float*)d_in[27];
  const float* tr_ln1g   = (const float*)d_in[28];
  const float* tr_ln1b   = (const float*)d_in[29];
  const float* tr_ln2g   = (const float*)d_in[30];
  const float* tr_ln2b   = (const float*)d_in[31];

  float* ws   = (float*)d_ws;
  float* SAIN = ws + OFF_SAIN;
  float* H    = ws + OFF_H;
  float* HP   = ws + OFF_HP;
  float* GX   = ws + OFF_GX;
  float* HS   = ws + OFF_HS;
  float* TIN  = ws + OFF_TIN;
  float* TOUT = ws + OFF_TOUT;
  float* QKV  = ws + OFF_QKV;
  float* CTX  = ws + OFF_CTX;
  unsigned short* SABF = (unsigned short*)(ws + OFF_SABF);  // bf16 sain (HP region, dead until k5b)
  unsigned short* WBT  = (unsigned short*)(ws + OFF_WBT);   // bf16 W^T (GX region, dead until k6)
  float* DEMB = ws + OFF_DEMB;
  float* F1   = ws + OFF_F1;
  float* F2   = ws + OFF_F2;
  float* ATT  = ws + OFF_ATT;
  float* WA   = ws + OFF_WA;
  float* dout = (float*)d_out;

  k0_demb<<<1, 512, 0, stream>>>(de, dp_w, dp_b, DEMB);
  k1_sain<<<dim3(100, 8), 256, 0, stream>>>(x, cond_info, cond_w, cond_b, DEMB, SAIN);
  kconv_a<<<5000, 256, 0, stream>>>(SAIN, SABF);
  kconv_w<<<dim3(100, 100), 256, 0, stream>>>(sa_W, WBT);
  kwa<<<1600, 256, 0, stream>>>(sa_W, sa_a, WA);
  k3_mfma<<<dim3(50, 10), 256, 0, stream>>>(SABF, WBT, H);
  k4_f12<<<800, 256, 0, stream>>>(SAIN, WA, F1, F2);
  k5_att<<<8, 128, 0, stream>>>(F1, F2, ATT);
  k5b_hprime<<<dim3(100, 8), 256, 0, stream>>>(H, ATT, HP);
  k6_gx<<<800, 256, 0, stream>>>(HP, lstm_Wih, lstm_bih, lstm_bhh, GX);
  k7_lstm<<<100, 256, 0, stream>>>(GX, lstm_Whh, HS);
  k8_y2<<<800, 256, 0, stream>>>(HS, lin_w, lin_b, TIN);
  k9a_qkv<<<800, 256, 0, stream>>>(TIN, tr_in_w, tr_in_b, QKV);
  k9b_attn<<<dim3(8, 800), 256, 0, stream>>>(QKV, CTX);
  k9c_ffn<<<800, 256, 0, stream>>>(TIN, CTX, TOUT, tr_out_w, tr_out_b,
                                   tr_f1w, tr_f1b, tr_f2w, tr_f2b,
                                   tr_ln1g, tr_ln1b, tr_ln2g, tr_ln2b);
  k10_final<<<dim3(100, 8), 256, 0, stream>>>(TOUT, x, mid_w, mid_b, out_w, out_b, dout);
}